// Round 2
// baseline (505.051 us; speedup 1.0000x reference)
//
#include <hip/hip_runtime.h>
#include <hip/hip_bf16.h>

// TT-chain: N=65536, L=128, D=4, R=8, O=2.
//   m = x[n,0] @ core_first[0]                       (1x4 @ 4x8)
//   for c in 0..125: m[l] = sum_{k,j} m[k]*cm[c,k,j,l]*x[n,c+1,j]
//   out[n,:] = sum_{k,j} m[k]*cl[k,j,:]*x[n,127,j]
// cm[:, :, 3, :] == I (padding=True) -> j=3 term is x.w * m[l] (224 MAC/step).
//
// R1 scheme: 4 lanes per sample (lane q handles l = 2q, 2q+1). Per step the
// full m[0..8) is rebuilt in every lane via a 6-swizzle butterfly (xor1, xor2
// within 4-lane groups). The butterfly leaves m-values in lane-dependent slot
// order K(q)[2p+b] = 2*(q^p)+b; that permutation is folded into a pre-packed
// core layout Cp[c][q][p][j] (float4 = C[{K[2p],K[2p+1]}, j, {2q,2q+1}]) so
// the hot loop reads 12 float4 from ONE per-lane base + immediate offsets.
// 262144 threads -> 16 waves/CU (vs 4 before); core loads are vector L1 hits
// instead of serialized scalar loads.

#define NTHREADS 256

__device__ __forceinline__ float swz_xor1(float v) {
    return __int_as_float(__builtin_amdgcn_ds_swizzle(__float_as_int(v), 0x041F));
}
__device__ __forceinline__ float swz_xor2(float v) {
    return __int_as_float(__builtin_amdgcn_ds_swizzle(__float_as_int(v), 0x081F));
}

// Pack cm[126,8,4,8] -> Cp[c][q][p*3+j] float4, c-major stride 48 float4.
// Cp[c][q][p*3+j] = ( cm[c, 2*(q^p)+0, j, 2q], cm[c, 2*(q^p)+0, j, 2q+1],
//                     cm[c, 2*(q^p)+1, j, 2q], cm[c, 2*(q^p)+1, j, 2q+1] )
__global__ __launch_bounds__(NTHREADS) void pack_cores(
    const float* __restrict__ cm, float4* __restrict__ cp)
{
    int t = blockIdx.x * NTHREADS + threadIdx.x;
    if (t >= 126 * 48) return;
    int c = t / 48;
    int r = t % 48;
    int q = r / 12;
    int pj = r % 12;
    int p = pj / 3;
    int j = pj % 3;
    int k0 = 2 * (q ^ p);
    int l0 = 2 * q;
    const float* base = cm + (size_t)c * 256;
    float4 f;
    f.x = base[(k0 + 0) * 32 + j * 8 + l0 + 0];
    f.y = base[(k0 + 0) * 32 + j * 8 + l0 + 1];
    f.z = base[(k0 + 1) * 32 + j * 8 + l0 + 0];
    f.w = base[(k0 + 1) * 32 + j * 8 + l0 + 1];
    cp[t] = f;
}

__global__ __launch_bounds__(NTHREADS) void tt_chain4(
    const float* __restrict__ x,    // [N,128,4]
    const float4* __restrict__ cp,  // packed cores, 126*48 float4
    const float* __restrict__ cf,   // [4,8]
    const float* __restrict__ cl,   // [8,4,2]
    float* __restrict__ out,        // [N,2]
    int N)
{
    const int gid = blockIdx.x * NTHREADS + threadIdx.x;
    const int n = gid >> 2;
    const int q = gid & 3;
    if (n >= N) return;

    const float4* __restrict__ xr = reinterpret_cast<const float4*>(x) + (size_t)n * 128;
    const float4* __restrict__ cpr = cp + q * 12;

    // init: m[2q+b] = sum_j cf[j*8 + 2q+b] * x0[j]
    const float4 x0 = xr[0];
    float m0, m1;
    {
        const int i0 = 2 * q;
        m0 = fmaf(cf[i0],      x0.x, fmaf(cf[8 + i0],  x0.y,
             fmaf(cf[16 + i0], x0.z,      cf[24 + i0] * x0.w)));
        m1 = fmaf(cf[i0 + 1],      x0.x, fmaf(cf[8 + i0 + 1],  x0.y,
             fmaf(cf[16 + i0 + 1], x0.z,      cf[24 + i0 + 1] * x0.w)));
    }

    float4 xt = xr[1];

    for (int c = 0; c < 126; ++c) {
        // butterfly broadcast: slots s[0..7] hold m[K(q)[i]]
        float s2 = swz_xor1(m0);
        float s3 = swz_xor1(m1);
        float s4 = swz_xor2(m0);
        float s5 = swz_xor2(m1);
        float s6 = swz_xor2(s2);
        float s7 = swz_xor2(s3);

        float4 xn = xr[c + 2];   // c<=125 -> max index 127 (consumed by epilogue)

        float4 F0  = cpr[0],  F1  = cpr[1],  F2  = cpr[2];
        float4 F3  = cpr[3],  F4  = cpr[4],  F5  = cpr[5];
        float4 F6  = cpr[6],  F7  = cpr[7],  F8  = cpr[8];
        float4 F9  = cpr[9],  F10 = cpr[10], F11 = cpr[11];

        float v0a, v0b, v1a, v1b, v2a, v2b;
        // p=0 (slots m0,m1)
        v0a = m0 * F0.x;  v0b = m0 * F0.y;
        v1a = m0 * F1.x;  v1b = m0 * F1.y;
        v2a = m0 * F2.x;  v2b = m0 * F2.y;
        v0a = fmaf(m1, F0.z, v0a);  v0b = fmaf(m1, F0.w, v0b);
        v1a = fmaf(m1, F1.z, v1a);  v1b = fmaf(m1, F1.w, v1b);
        v2a = fmaf(m1, F2.z, v2a);  v2b = fmaf(m1, F2.w, v2b);
        // p=1 (slots s2,s3)
        v0a = fmaf(s2, F3.x, v0a);  v0b = fmaf(s2, F3.y, v0b);
        v1a = fmaf(s2, F4.x, v1a);  v1b = fmaf(s2, F4.y, v1b);
        v2a = fmaf(s2, F5.x, v2a);  v2b = fmaf(s2, F5.y, v2b);
        v0a = fmaf(s3, F3.z, v0a);  v0b = fmaf(s3, F3.w, v0b);
        v1a = fmaf(s3, F4.z, v1a);  v1b = fmaf(s3, F4.w, v1b);
        v2a = fmaf(s3, F5.z, v2a);  v2b = fmaf(s3, F5.w, v2b);
        // p=2 (slots s4,s5)
        v0a = fmaf(s4, F6.x, v0a);  v0b = fmaf(s4, F6.y, v0b);
        v1a = fmaf(s4, F7.x, v1a);  v1b = fmaf(s4, F7.y, v1b);
        v2a = fmaf(s4, F8.x, v2a);  v2b = fmaf(s4, F8.y, v2b);
        v0a = fmaf(s5, F6.z, v0a);  v0b = fmaf(s5, F6.w, v0b);
        v1a = fmaf(s5, F7.z, v1a);  v1b = fmaf(s5, F7.w, v1b);
        v2a = fmaf(s5, F8.z, v2a);  v2b = fmaf(s5, F8.w, v2b);
        // p=3 (slots s6,s7)
        v0a = fmaf(s6, F9.x,  v0a); v0b = fmaf(s6, F9.y,  v0b);
        v1a = fmaf(s6, F10.x, v1a); v1b = fmaf(s6, F10.y, v1b);
        v2a = fmaf(s6, F11.x, v2a); v2b = fmaf(s6, F11.y, v2b);
        v0a = fmaf(s7, F9.z,  v0a); v0b = fmaf(s7, F9.w,  v0b);
        v1a = fmaf(s7, F10.z, v1a); v1b = fmaf(s7, F10.w, v1b);
        v2a = fmaf(s7, F11.z, v2a); v2b = fmaf(s7, F11.w, v2b);

        // identity (j=3) term is x.w * own m
        float nm0 = fmaf(xt.x, v0a, fmaf(xt.y, v1a, fmaf(xt.z, v2a, xt.w * m0)));
        float nm1 = fmaf(xt.x, v0b, fmaf(xt.y, v1b, fmaf(xt.z, v2b, xt.w * m1)));
        m0 = nm0;
        m1 = nm1;

        cpr += 48;
        xt = xn;
    }

    // epilogue: out[n, l2] for l2 = q in {0,1}; xt == xr[127]
    {
        float s2 = swz_xor1(m0);
        float s3 = swz_xor1(m1);
        float s4 = swz_xor2(m0);
        float s5 = swz_xor2(m1);
        float s6 = swz_xor2(s2);
        float s7 = swz_xor2(s3);
        float sl[8] = { m0, m1, s2, s3, s4, s5, s6, s7 };

        if (q < 2) {
            float a0 = 0.f, a1 = 0.f, a2 = 0.f, a3 = 0.f;
            #pragma unroll
            for (int p = 0; p < 4; ++p) {
                #pragma unroll
                for (int b = 0; b < 2; ++b) {
                    const int k = 2 * (q ^ p) + b;
                    const float mv = sl[2 * p + b];
                    a0 = fmaf(mv, cl[k * 8 + 0 + q], a0);
                    a1 = fmaf(mv, cl[k * 8 + 2 + q], a1);
                    a2 = fmaf(mv, cl[k * 8 + 4 + q], a2);
                    a3 = fmaf(mv, cl[k * 8 + 6 + q], a3);
                }
            }
            const float o = fmaf(xt.x, a0, fmaf(xt.y, a1, fmaf(xt.z, a2, xt.w * a3)));
            out[2 * (size_t)n + q] = o;
        }
    }
}

extern "C" void kernel_launch(void* const* d_in, const int* in_sizes, int n_in,
                              void* d_out, int out_size, void* d_ws, size_t ws_size,
                              hipStream_t stream) {
    const float* x  = (const float*)d_in[0];   // [N,128,4]
    const float* cf = (const float*)d_in[1];   // [1,4,8]
    const float* cm = (const float*)d_in[2];   // [126,8,4,8]
    const float* cl = (const float*)d_in[3];   // [8,4,2]
    float* out = (float*)d_out;                // [N,2]

    const int N = in_sizes[0] / (128 * 4);

    float4* cp = (float4*)d_ws;  // 126*48*16 B = 96768 B

    pack_cores<<<(126 * 48 + NTHREADS - 1) / NTHREADS, NTHREADS, 0, stream>>>(cm, cp);

    const int total = N * 4;
    tt_chain4<<<(total + NTHREADS - 1) / NTHREADS, NTHREADS, 0, stream>>>(
        x, cp, cf, cl, out, N);
}

// Round 3
// 286.005 us; speedup vs baseline: 1.7659x; 1.7659x over previous
//
#include <hip/hip_runtime.h>
#include <hip/hip_bf16.h>

// TT-chain: N=65536, L=128, D=4, R=8, O=2.
//   m = x[n,0] @ core_first[0]
//   for c in 0..125: m[l] = sum_{k,j} m[k]*cm[c,k,j,l]*x[n,c+1,j]
//   out[n,:] = sum_{k,j} m[k]*cl[k,j,:]*x[n,127,j]
// cm[:, :, 3, :] == I (padding=True) -> j=3 term is x.w*m[l]  (224 MAC/step).
//
// R2 design: one thread per sample (R1 layout), but cores flow through
// double-buffered LDS (global_load_lds staging by wave 0, __syncthreads per
// 8-step chunk) instead of the scalar pipe. Step reads are wave-uniform
// ds_read_b128 broadcasts whose addresses don't depend on the recurrence ->
// schedulable arbitrarily early. Issue floor per step: 224 v_fma (448 cyc)
// + 48 ds_read. x is register double-buffered as in R1.

#define NTHREADS 256
#define STEPS_PER_CHUNK 8
#define CHUNK_FLOATS (STEPS_PER_CHUNK * 192)   // 1536 floats = 6144 B
#define CHUNK_BYTES  (CHUNK_FLOATS * 4)

// Pack cm[126,8,4,8] -> cmp[c][k][j][l] with j<3 only: 192 floats per core.
__global__ __launch_bounds__(NTHREADS) void pack_cores(
    const float* __restrict__ cm, float* __restrict__ cmp)
{
    int t = blockIdx.x * NTHREADS + threadIdx.x;
    if (t >= 126 * 192) return;
    int c = t / 192;
    int r = t % 192;          // k*24 + j*8 + l
    int k = r / 24;
    int jl = r % 24;
    int j = jl / 8;
    int l = jl % 8;
    cmp[t] = cm[c * 256 + k * 32 + j * 8 + l];
}

__device__ __forceinline__ void gll16(const void* g, void* l) {
    __builtin_amdgcn_global_load_lds(
        (const __attribute__((address_space(1))) unsigned int*)g,
        (__attribute__((address_space(3))) unsigned int*)l, 16, 0, 0);
}

__global__ __launch_bounds__(NTHREADS, 1) void tt_chain_lds(
    const float* __restrict__ x,    // [N,128,4]
    const float* __restrict__ cmp,  // packed cores, 126*192 floats (+pad)
    const float* __restrict__ cf,   // [4,8]
    const float* __restrict__ cl,   // [8,4,2]
    float* __restrict__ out)        // [N,2]
{
    __shared__ __align__(16) float smem[2 * CHUNK_FLOATS];   // 12 KB

    const int tid = threadIdx.x;
    const int n = blockIdx.x * NTHREADS + tid;   // grid exactly covers N

    const float4* __restrict__ xr = reinterpret_cast<const float4*>(x) + (size_t)n * 128;
    const char* cmpB = reinterpret_cast<const char*>(cmp);

    // ---- prologue: stage chunk 0, load x0 + chunk-0 x regs ----
    if (tid < 64) {
        #pragma unroll
        for (int i = 0; i < 6; ++i)
            gll16(cmpB + i * 1024 + tid * 16, &smem[i * 256]);
    }
    const float4 x0 = xr[0];
    float4 cur[8], nxt[8];
    #pragma unroll
    for (int i = 0; i < 8; ++i) cur[i] = xr[1 + i];

    float m[8];
    #pragma unroll
    for (int k = 0; k < 8; ++k)
        m[k] = fmaf(cf[k], x0.x,
               fmaf(cf[8 + k], x0.y,
               fmaf(cf[16 + k], x0.z, cf[24 + k] * x0.w)));

    __syncthreads();   // chunk 0 staged (wave0 vmcnt drains before its barrier)

    // one recurrence step; Bs = 192-float core block in LDS (wave-uniform)
    auto step = [&](const float* __restrict__ Bs, const float4 xt) {
        float nm[8];
        #pragma unroll
        for (int l = 0; l < 8; ++l) nm[l] = xt.w * m[l];
        #pragma unroll
        for (int k = 0; k < 8; ++k) {
            const float mkx = m[k] * xt.x;
            const float mky = m[k] * xt.y;
            const float mkz = m[k] * xt.z;
            const float4 a0 = *(const float4*)(Bs + k * 24 + 0);
            const float4 a1 = *(const float4*)(Bs + k * 24 + 4);
            const float4 b0 = *(const float4*)(Bs + k * 24 + 8);
            const float4 b1 = *(const float4*)(Bs + k * 24 + 12);
            const float4 c0 = *(const float4*)(Bs + k * 24 + 16);
            const float4 c1 = *(const float4*)(Bs + k * 24 + 20);
            nm[0] = fmaf(mkx, a0.x, nm[0]); nm[1] = fmaf(mkx, a0.y, nm[1]);
            nm[2] = fmaf(mkx, a0.z, nm[2]); nm[3] = fmaf(mkx, a0.w, nm[3]);
            nm[4] = fmaf(mkx, a1.x, nm[4]); nm[5] = fmaf(mkx, a1.y, nm[5]);
            nm[6] = fmaf(mkx, a1.z, nm[6]); nm[7] = fmaf(mkx, a1.w, nm[7]);
            nm[0] = fmaf(mky, b0.x, nm[0]); nm[1] = fmaf(mky, b0.y, nm[1]);
            nm[2] = fmaf(mky, b0.z, nm[2]); nm[3] = fmaf(mky, b0.w, nm[3]);
            nm[4] = fmaf(mky, b1.x, nm[4]); nm[5] = fmaf(mky, b1.y, nm[5]);
            nm[6] = fmaf(mky, b1.z, nm[6]); nm[7] = fmaf(mky, b1.w, nm[7]);
            nm[0] = fmaf(mkz, c0.x, nm[0]); nm[1] = fmaf(mkz, c0.y, nm[1]);
            nm[2] = fmaf(mkz, c0.z, nm[2]); nm[3] = fmaf(mkz, c0.w, nm[3]);
            nm[4] = fmaf(mkz, c1.x, nm[4]); nm[5] = fmaf(mkz, c1.y, nm[5]);
            nm[6] = fmaf(mkz, c1.z, nm[6]); nm[7] = fmaf(mkz, c1.w, nm[7]);
        }
        #pragma unroll
        for (int l = 0; l < 8; ++l) m[l] = nm[l];
    };

    // ---- chunks 0..14 (8 steps each; stage ch+1; prefetch x for ch+1) ----
    for (int ch = 0; ch < 15; ++ch) {
        const int nb = (ch + 1) & 1;
        if (tid < 64) {
            const char* g = cmpB + (size_t)(ch + 1) * CHUNK_BYTES;
            #pragma unroll
            for (int i = 0; i < 6; ++i)
                gll16(g + i * 1024 + tid * 16, &smem[nb * CHUNK_FLOATS + i * 256]);
        }
        #pragma unroll
        for (int i = 0; i < 8; ++i) {
            int t = (ch + 1) * 8 + 1 + i;
            if (t > 127) t = 127;
            nxt[i] = xr[t];
        }

        const float* B = &smem[(ch & 1) * CHUNK_FLOATS];
        #pragma unroll
        for (int s = 0; s < 8; ++s) step(B + s * 192, cur[s]);

        __syncthreads();   // drains this wave's staging+x loads, syncs buffers
        #pragma unroll
        for (int i = 0; i < 8; ++i) cur[i] = nxt[i];
    }

    // ---- tail chunk 15: steps c=120..125 (xt = cur[0..5]) ----
    {
        const float* B = &smem[CHUNK_FLOATS];   // 15&1 == 1
        #pragma unroll
        for (int s = 0; s < 6; ++s) step(B + s * 192, cur[s]);
    }

    // ---- epilogue: out[n,o] = sum_{k,j} m[k]*cl[k*8+j*2+o]*x[n,127,j] ----
    {
        const float4 xl = cur[6];   // xr[127]
        const float xj[4] = { xl.x, xl.y, xl.z, xl.w };
        float o0 = 0.f, o1 = 0.f;
        #pragma unroll
        for (int j = 0; j < 4; ++j) {
            float v0 = 0.f, v1 = 0.f;
            #pragma unroll
            for (int k = 0; k < 8; ++k) {
                v0 = fmaf(m[k], cl[k * 8 + j * 2 + 0], v0);
                v1 = fmaf(m[k], cl[k * 8 + j * 2 + 1], v1);
            }
            o0 = fmaf(xj[j], v0, o0);
            o1 = fmaf(xj[j], v1, o1);
        }
        reinterpret_cast<float2*>(out)[n] = make_float2(o0, o1);
    }
}

extern "C" void kernel_launch(void* const* d_in, const int* in_sizes, int n_in,
                              void* d_out, int out_size, void* d_ws, size_t ws_size,
                              hipStream_t stream) {
    const float* x  = (const float*)d_in[0];   // [N,128,4]
    const float* cf = (const float*)d_in[1];   // [1,4,8]
    const float* cm = (const float*)d_in[2];   // [126,8,4,8]
    const float* cl = (const float*)d_in[3];   // [8,4,2]
    float* out = (float*)d_out;                // [N,2]

    const int N = in_sizes[0] / (128 * 4);

    // packed cores: 126*192 floats = 96768 B; chunk 15 staging overreads
    // 1536 B of pad (never computed with) -> keep 98304 B of ws.
    float* cmp = (float*)d_ws;

    pack_cores<<<(126 * 192 + NTHREADS - 1) / NTHREADS, NTHREADS, 0, stream>>>(cm, cmp);

    tt_chain_lds<<<N / NTHREADS, NTHREADS, 0, stream>>>(x, cmp, cf, cl, out);
}